// Round 5
// baseline (1317.579 us; speedup 1.0000x reference)
//
#include <hip/hip_runtime.h>

#define N_IN   100000
#define N_OUT  400000
#define KK     8
#define PP     100000
#define C_IN   128
#define C_OUTC 64
#define C_SKIP 64
#define EPS_BN 1e-5f

// ---------------------------------------------------------------------------
// Scatter: y[out_idx] += x[in_idx] @ W_deconv[k]
// blockIdx.y = k. Weights in LDS interleaved as wq[iq][c] = float4 of
// W[4iq..4iq+3][c] -> one ds_read_b128 per 4 input channels (stride-16B
// canonical conflict-free pattern). x rows via per-lane-uniform float4
// vector loads (VGPR addrs -> broadcast). 4 groups x 8 pairs per
// super-iteration; ALL 32 atomics issued at the end so the in-order vmcnt
// release chain (atomics block younger loads' retirement) is paid once per
// ~8k VALU-cycles instead of once per 2k.
// ---------------------------------------------------------------------------
__global__ __launch_bounds__(512, 4) void scatter_kernel(
    const float* __restrict__ x, const float* __restrict__ Wd,
    const int* __restrict__ in_idx, const int* __restrict__ out_idx,
    float* __restrict__ y)
{
    __shared__ float4 wq[(C_IN / 4) * C_OUTC];     // 32 KB
    const int k = blockIdx.y;
    {
        const float* __restrict__ Wk = Wd + (size_t)k * (C_IN * C_OUTC);
        for (int e = threadIdx.x; e < C_IN * C_OUTC; e += 512) {
            const int i = e >> 6, c = e & 63;
            ((float*)&wq[(i >> 2) * C_OUTC + c])[i & 3] = Wk[e];
        }
    }
    __syncthreads();

    const int lane = threadIdx.x & 63;
    const int wv   = (int)((blockIdx.x * 512 + threadIdx.x) >> 6);  // VGPR wave id
    const int nw   = (int)gridDim.x * 8;
    const int4* __restrict__ ii4 = (const int4*)(in_idx + k * PP);
    const int4* __restrict__ oi4 = (const int4*)(out_idx + k * PP);
    const float4* __restrict__ wrow = wq + lane;   // wrow[iq*64] = this lane's w4
    const int nsup = PP / 32;                      // 3125 super-groups

    for (int s = wv; s < nsup; s += nw) {
        float acc[4][8];

        #pragma unroll
        for (int grp = 0; grp < 4; ++grp) {
            const int4 ia = ii4[s * 8 + grp * 2];
            const int4 ib = ii4[s * 8 + grp * 2 + 1];
            const float4* __restrict__ x0 = (const float4*)(x + (size_t)ia.x * C_IN);
            const float4* __restrict__ x1 = (const float4*)(x + (size_t)ia.y * C_IN);
            const float4* __restrict__ x2 = (const float4*)(x + (size_t)ia.z * C_IN);
            const float4* __restrict__ x3 = (const float4*)(x + (size_t)ia.w * C_IN);
            const float4* __restrict__ x4 = (const float4*)(x + (size_t)ib.x * C_IN);
            const float4* __restrict__ x5 = (const float4*)(x + (size_t)ib.y * C_IN);
            const float4* __restrict__ x6 = (const float4*)(x + (size_t)ib.z * C_IN);
            const float4* __restrict__ x7 = (const float4*)(x + (size_t)ib.w * C_IN);

            float a0=0.f,a1=0.f,a2=0.f,a3=0.f,a4=0.f,a5=0.f,a6=0.f,a7=0.f;
            #pragma unroll 2
            for (int iq = 0; iq < C_IN / 4; ++iq) {
                const float4 w4 = wrow[iq * C_OUTC];           // ds_read_b128
                const float4 v0 = x0[iq]; const float4 v1 = x1[iq];
                const float4 v2 = x2[iq]; const float4 v3 = x3[iq];
                const float4 v4 = x4[iq]; const float4 v5 = x5[iq];
                const float4 v6 = x6[iq]; const float4 v7 = x7[iq];
                a0 = fmaf(v0.x, w4.x, a0); a0 = fmaf(v0.y, w4.y, a0);
                a0 = fmaf(v0.z, w4.z, a0); a0 = fmaf(v0.w, w4.w, a0);
                a1 = fmaf(v1.x, w4.x, a1); a1 = fmaf(v1.y, w4.y, a1);
                a1 = fmaf(v1.z, w4.z, a1); a1 = fmaf(v1.w, w4.w, a1);
                a2 = fmaf(v2.x, w4.x, a2); a2 = fmaf(v2.y, w4.y, a2);
                a2 = fmaf(v2.z, w4.z, a2); a2 = fmaf(v2.w, w4.w, a2);
                a3 = fmaf(v3.x, w4.x, a3); a3 = fmaf(v3.y, w4.y, a3);
                a3 = fmaf(v3.z, w4.z, a3); a3 = fmaf(v3.w, w4.w, a3);
                a4 = fmaf(v4.x, w4.x, a4); a4 = fmaf(v4.y, w4.y, a4);
                a4 = fmaf(v4.z, w4.z, a4); a4 = fmaf(v4.w, w4.w, a4);
                a5 = fmaf(v5.x, w4.x, a5); a5 = fmaf(v5.y, w4.y, a5);
                a5 = fmaf(v5.z, w4.z, a5); a5 = fmaf(v5.w, w4.w, a5);
                a6 = fmaf(v6.x, w4.x, a6); a6 = fmaf(v6.y, w4.y, a6);
                a6 = fmaf(v6.z, w4.z, a6); a6 = fmaf(v6.w, w4.w, a6);
                a7 = fmaf(v7.x, w4.x, a7); a7 = fmaf(v7.y, w4.y, a7);
                a7 = fmaf(v7.z, w4.z, a7); a7 = fmaf(v7.w, w4.w, a7);
            }
            acc[grp][0]=a0; acc[grp][1]=a1; acc[grp][2]=a2; acc[grp][3]=a3;
            acc[grp][4]=a4; acc[grp][5]=a5; acc[grp][6]=a6; acc[grp][7]=a7;
        }

        // Hoist ALL output-index loads before the first atomic (no
        // atomic-before-load in the FIFO for this super-iteration).
        int4 oa[4], ob[4];
        #pragma unroll
        for (int grp = 0; grp < 4; ++grp) {
            oa[grp] = oi4[s * 8 + grp * 2];
            ob[grp] = oi4[s * 8 + grp * 2 + 1];
        }
        #pragma unroll
        for (int grp = 0; grp < 4; ++grp) {
            atomicAdd(&y[(size_t)oa[grp].x * C_OUTC + lane], acc[grp][0]);
            atomicAdd(&y[(size_t)oa[grp].y * C_OUTC + lane], acc[grp][1]);
            atomicAdd(&y[(size_t)oa[grp].z * C_OUTC + lane], acc[grp][2]);
            atomicAdd(&y[(size_t)oa[grp].w * C_OUTC + lane], acc[grp][3]);
            atomicAdd(&y[(size_t)ob[grp].x * C_OUTC + lane], acc[grp][4]);
            atomicAdd(&y[(size_t)ob[grp].y * C_OUTC + lane], acc[grp][5]);
            atomicAdd(&y[(size_t)ob[grp].z * C_OUTC + lane], acc[grp][6]);
            atomicAdd(&y[(size_t)ob[grp].w * C_OUTC + lane], acc[grp][7]);
        }
    }
}

// ---------------------------------------------------------------------------
// Per-channel sum / sumsq over y (float4 per thread) -> stats[0:64] | [64:128]
// ---------------------------------------------------------------------------
__global__ __launch_bounds__(256) void stats_kernel(
    const float* __restrict__ y, float* __restrict__ stats)
{
    const int tid = threadIdx.x;
    const int cq  = tid & 15;                          // channel quad 0..15
    const int rid = (int)((blockIdx.x * 256 + tid) >> 4);
    const int nr  = (int)(gridDim.x * 256) >> 4;
    const float4* __restrict__ y4 = (const float4*)y;

    float sx=0,sy=0,sz=0,sw=0, qx=0,qy=0,qz=0,qw=0;
    for (int r = rid; r < N_OUT; r += nr) {
        const float4 v = y4[(size_t)r * 16 + cq];
        sx += v.x; sy += v.y; sz += v.z; sw += v.w;
        qx = fmaf(v.x, v.x, qx); qy = fmaf(v.y, v.y, qy);
        qz = fmaf(v.z, v.z, qz); qw = fmaf(v.w, v.w, qw);
    }
    __shared__ float ls[4 * 256];
    __shared__ float lq[4 * 256];
    ls[0*256+tid]=sx; ls[1*256+tid]=sy; ls[2*256+tid]=sz; ls[3*256+tid]=sw;
    lq[0*256+tid]=qx; lq[1*256+tid]=qy; lq[2*256+tid]=qz; lq[3*256+tid]=qw;
    __syncthreads();
    for (int off = 128; off >= 16; off >>= 1) {
        if (tid < off) {
            #pragma unroll
            for (int c = 0; c < 4; ++c) {
                ls[c*256+tid] += ls[c*256+tid+off];
                lq[c*256+tid] += lq[c*256+tid+off];
            }
        }
        __syncthreads();
    }
    if (tid < 16) {
        #pragma unroll
        for (int c = 0; c < 4; ++c) {
            atomicAdd(&stats[tid * 4 + c],           ls[c*256+tid]);
            atomicAdd(&stats[C_OUTC + tid * 4 + c],  lq[c*256+tid]);
        }
    }
}

// ---------------------------------------------------------------------------
// Fold BN into fuse-friendly constants.
//  s[i]   = gamma*rsqrt(var+eps)          (sc[0:64])   -> scales Wf rows
//  nb[i]  = -(beta - mean*s)/s            (sc[64:128])
//  bias[c]= sum_i b_i * Wf[i][c]          (sc[128:192])-> accumulator seed
// Derivation: relu(y*s+b) @ W = max(y, -b/s) @ (diag(s)W) + (b @ W), s > 0.
// ---------------------------------------------------------------------------
__global__ void finalize_kernel(const float* __restrict__ stats,
                                const float* __restrict__ gamma,
                                const float* __restrict__ beta,
                                const float* __restrict__ Wf,
                                float* __restrict__ sc)
{
    __shared__ float bsh[C_OUTC];
    const int c = threadIdx.x;                 // 64 threads
    const float inv_n = 1.0f / (float)N_OUT;
    const float mean  = stats[c] * inv_n;
    const float var   = stats[C_OUTC + c] * inv_n - mean * mean;
    const float s     = gamma[c] * rsqrtf(var + EPS_BN);
    const float b     = beta[c] - mean * s;
    sc[c]            = s;
    sc[C_OUTC + c]   = -b / s;
    bsh[c] = b;
    __syncthreads();
    float acc = 0.f;
    for (int i = 0; i < C_OUTC; ++i)
        acc = fmaf(bsh[i], Wf[i * C_OUTC + c], acc);
    sc[2 * C_OUTC + c] = acc;
}

// ---------------------------------------------------------------------------
// Fused BN+ReLU+concat+linear, in-place on y.
// Wf staged in LDS with BN scale pre-multiplied into the y-half rows;
// accumulator seeded with the BN bias term. Rows via scalar loads
// (sequential -> sL1-friendly). Each wave fully reads its 8 rows before
// overwriting them.
// ---------------------------------------------------------------------------
__global__ __launch_bounds__(512) void fuse_kernel(
    float* __restrict__ y, const float* __restrict__ skip,
    const float* __restrict__ Wf, const float* __restrict__ sc)
{
    __shared__ float wlds[C_IN * C_OUTC];          // [i][c], y-half pre-scaled
    __shared__ float nb[C_OUTC];
    for (int e = threadIdx.x; e < C_IN * C_OUTC; e += 512) {
        const int i = e >> 6;
        const float w = Wf[e];
        wlds[e] = (i < C_OUTC) ? w * sc[i] : w;
    }
    if (threadIdx.x < C_OUTC) nb[threadIdx.x] = sc[C_OUTC + threadIdx.x];
    __syncthreads();

    const int lane = threadIdx.x & 63;
    int wv = (int)((blockIdx.x * 512 + threadIdx.x) >> 6);
    wv = __builtin_amdgcn_readfirstlane(wv);       // SGPR wave id -> s_load rows
    const int nw = (int)gridDim.x * 8;
    const float bias0 = sc[2 * C_OUTC + lane];

    for (int g = wv; g < N_OUT / 8; g += nw) {
        const float* __restrict__ yr = y    + (size_t)g * 8 * C_OUTC;
        const float* __restrict__ sr = skip + (size_t)g * 8 * C_SKIP;

        float acc[8];
        #pragma unroll
        for (int r = 0; r < 8; ++r) acc[r] = bias0;

        #pragma unroll 8
        for (int i = 0; i < C_OUTC; ++i) {
            const float w = wlds[i * C_OUTC + lane];
            const float t = nb[i];
            #pragma unroll
            for (int r = 0; r < 8; ++r)
                acc[r] = fmaf(fmaxf(yr[r * C_OUTC + i], t), w, acc[r]);
        }
        #pragma unroll 8
        for (int i = 0; i < C_SKIP; ++i) {
            const float w = wlds[(C_OUTC + i) * C_OUTC + lane];
            #pragma unroll
            for (int r = 0; r < 8; ++r)
                acc[r] = fmaf(sr[r * C_SKIP + i], w, acc[r]);
        }
        #pragma unroll
        for (int r = 0; r < 8; ++r)
            y[((size_t)g * 8 + r) * C_OUTC + lane] = acc[r];
    }
}

// ---------------------------------------------------------------------------
extern "C" void kernel_launch(void* const* d_in, const int* in_sizes, int n_in,
                              void* d_out, int out_size, void* d_ws, size_t ws_size,
                              hipStream_t stream)
{
    const float* x      = (const float*)d_in[0];
    const float* skip   = (const float*)d_in[1];
    const float* Wd     = (const float*)d_in[2];
    const float* gamma  = (const float*)d_in[3];
    const float* beta   = (const float*)d_in[4];
    const float* Wf     = (const float*)d_in[5];
    const int*   in_idx  = (const int*)d_in[6];
    const int*   out_idx = (const int*)d_in[7];

    float* y     = (float*)d_out;            // y lives in d_out (same shape)
    float* stats = (float*)d_ws;             // 128 floats: sum | sumsq
    float* sc    = stats + 128;              // 192 floats: s | -b/s | bias

    hipMemsetAsync(d_out, 0, (size_t)N_OUT * C_OUTC * sizeof(float), stream);
    hipMemsetAsync(d_ws, 0, 128 * sizeof(float), stream);

    dim3 sgrid(128, KK, 1);                  // 1024 blocks, blockIdx.y = k
    scatter_kernel<<<sgrid, 512, 0, stream>>>(x, Wd, in_idx, out_idx, y);
    stats_kernel<<<2048, 256, 0, stream>>>(y, stats);
    finalize_kernel<<<1, 64, 0, stream>>>(stats, gamma, beta, Wf, sc);
    fuse_kernel<<<1024, 512, 0, stream>>>(y, skip, Wf, sc);
}